// Round 6
// baseline (89.133 us; speedup 1.0000x reference)
//
#include <hip/hip_runtime.h>

// Involution1d: B=16, CH=256, DIM=4096, G=16, K=7, PAD=3, hid=64, K*G=112.
// setup (split weights hi/lo bf16) -> kerngen (LDS-staged x + MFMA bf16
// split-precision, kern f16-pairs in ws) -> involution (memory-bound).
#define BB   16
#define CHN  256
#define DIMN 4096
#define KK   7
#define PADK 3
#define HID  64
#define KGN  112
#define RP   56        // kern rows as f16-pairs
#define LT   64        // locations per block tile
#define BN_EPS 1e-5f

typedef __fp16 half2_t __attribute__((ext_vector_type(2)));
typedef short  short8  __attribute__((ext_vector_type(8)));
typedef float  f32x4   __attribute__((ext_vector_type(4)));

union U32H2 { unsigned int u; half2_t h; };

static __device__ __forceinline__ unsigned int packf(float a, float b) {
    U32H2 t; t.h = __builtin_amdgcn_cvt_pkrtz(a, b); return t.u;
}
static __device__ __forceinline__ half2_t ash2(unsigned int u) { U32H2 t; t.u = u; return t.h; }
static __device__ __forceinline__ unsigned short bch(__bf16 h) {
    return __builtin_bit_cast(unsigned short, h);
}

// ---------------------------------------------------------------------------
// Split w1 [64][256] and w2 [112][64] into hi/lo bf16; precompute BN affine.
__global__ __launch_bounds__(256) void setup_k(
    const float* __restrict__ w1, const float* __restrict__ w2,
    const float* __restrict__ bn_gamma, const float* __restrict__ bn_beta,
    const float* __restrict__ bn_mean,  const float* __restrict__ bn_var,
    unsigned short* __restrict__ w1hi, unsigned short* __restrict__ w1lo,
    unsigned short* __restrict__ w2hi, unsigned short* __restrict__ w2lo,
    float* __restrict__ scb, float* __restrict__ shb) {
    int t = blockIdx.x * 256 + threadIdx.x;   // grid covers 16384
    if (t < HID * CHN) {
        float f = w1[t];
        __bf16 hi = (__bf16)f;
        w1hi[t] = bch(hi);
        w1lo[t] = bch((__bf16)(f - (float)hi));
    }
    if (t < KGN * HID) {
        float f = w2[t];
        __bf16 hi = (__bf16)f;
        w2hi[t] = bch(hi);
        w2lo[t] = bch((__bf16)(f - (float)hi));
    }
    if (t < HID) {
        float s = bn_gamma[t] * rsqrtf(bn_var[t] + BN_EPS);
        scb[t] = s;
        shb[t] = bn_beta[t] - bn_mean[t] * s;
    }
}

// ---------------------------------------------------------------------------
// MFMA kernel generator with LDS-staged x.
// Block = (b, 64-loc tile), 4 waves; wave w owns columns [16w, 16w+16).
// xs layout: [col][ch ^ xswz(col)] f32, 64 KiB; after a wave's last xs read,
// its per-col region is reused for the h tile (bf16 hi/lo) -- col-private,
// so no second barrier.
__global__ __launch_bounds__(256) void kerngen_k(
    const float* __restrict__ x,
    const unsigned short* __restrict__ w1hi, const unsigned short* __restrict__ w1lo,
    const float* __restrict__ b1,
    const float* __restrict__ scb, const float* __restrict__ shb,
    const unsigned short* __restrict__ w2hi, const unsigned short* __restrict__ w2lo,
    const float* __restrict__ b2,
    unsigned int* __restrict__ kern) {        // [16][56][4096] f16-pairs
    __shared__ float xs[LT * CHN];            // 64 KiB

    const int t    = threadIdx.x;
    const int lr   = t & 15;          // fragment row/col index
    const int lg   = (t >> 4) & 3;    // k-group
    const int w    = t >> 6;          // wave id
    const int b    = blockIdx.x >> 6;
    const int l0   = (blockIdx.x & 63) * LT;
    const int col  = 16 * w + lr;     // column within block tile (0..63)
    const int gcol = l0 + col;        // global location

    // ---- stage x[256 ch][64 cols] -> xs (transposed, swizzled), coalesced
    {
        const int cb   = t >> 4;              // 0..15
        const int col0 = (t & 15) * 4;
        const float* xg = x + (size_t)b * CHN * DIMN + l0 + col0;
#pragma unroll 4
        for (int i = 0; i < 16; ++i) {
            const int ch = 16 * i + cb;
            const float4 v = *(const float4*)(xg + (size_t)ch * DIMN);
#pragma unroll
            for (int c = 0; c < 4; ++c) {
                const int cc  = col0 + c;
                const int chs = ch ^ (((cc >> 3) & 7) << 3);
                xs[cc * CHN + chs] = (&v.x)[c];
            }
        }
    }
    __syncthreads();

    const int xswz = ((col >> 3) & 7) << 3;
    const int hswz = (col & 7) << 3;
    float* xcol = xs + col * CHN;

    // ---- Phase 1: h = w1 . x  (4 o-frags x 8 k-steps, split bf16) ----
    f32x4 acc[4];
#pragma unroll
    for (int of = 0; of < 4; ++of) acc[of] = (f32x4){0.f, 0.f, 0.f, 0.f};

#pragma unroll
    for (int ks = 0; ks < 8; ++ks) {
        const int ch0 = (32 * ks + 8 * lg) ^ xswz;    // 8-aligned, contiguous 8
        f32x4 va = *(const f32x4*)(xcol + ch0);
        f32x4 vb = *(const f32x4*)(xcol + ch0 + 4);
        short8 bhi, blo;
#pragma unroll
        for (int j = 0; j < 8; ++j) {
            float f = (j < 4) ? va[j] : vb[j - 4];
            __bf16 hi = (__bf16)f;
            bhi[j] = (short)bch(hi);
            blo[j] = (short)bch((__bf16)(f - (float)hi));
        }
#pragma unroll
        for (int of = 0; of < 4; ++of) {
            const int aoff = (16 * of + lr) * CHN + 32 * ks + 8 * lg;
            short8 ahi = *(const short8*)(w1hi + aoff);
            short8 alo = *(const short8*)(w1lo + aoff);
            acc[of] = __builtin_amdgcn_mfma_f32_16x16x32_bf16(ahi, bhi, acc[of], 0, 0, 0);
            acc[of] = __builtin_amdgcn_mfma_f32_16x16x32_bf16(ahi, blo, acc[of], 0, 0, 0);
            acc[of] = __builtin_amdgcn_mfma_f32_16x16x32_bf16(alo, bhi, acc[of], 0, 0, 0);
        }
    }

    // ---- bias + relu + BN; h -> LDS overlay (bf16 hi at dw 0..31, lo 32..63)
    unsigned int* hc = (unsigned int*)xcol;
#pragma unroll
    for (int of = 0; of < 4; ++of) {
#pragma unroll
        for (int p = 0; p < 2; ++p) {
            const int ov = 16 * of + 4 * lg + 2 * p;
            float h0 = fmaxf(acc[of][2 * p + 0] + b1[ov + 0], 0.f) * scb[ov + 0] + shb[ov + 0];
            float h1 = fmaxf(acc[of][2 * p + 1] + b1[ov + 1], 0.f) * scb[ov + 1] + shb[ov + 1];
            __bf16 h0h = (__bf16)h0; __bf16 h0l = (__bf16)(h0 - (float)h0h);
            __bf16 h1h = (__bf16)h1; __bf16 h1l = (__bf16)(h1 - (float)h1h);
            const int dv = (ov ^ hswz) >> 1;
            hc[dv]      = ((unsigned int)bch(h1h) << 16) | bch(h0h);
            hc[32 + dv] = ((unsigned int)bch(h1l) << 16) | bch(h0l);
        }
    }
    // producer == consumer (same lane) -> no barrier needed.

    // ---- Phase 2: kern = w2 . h  (7 r-frags x 2 k-steps, split bf16) ----
    f32x4 acc2[7];
#pragma unroll
    for (int rf = 0; rf < 7; ++rf) acc2[rf] = (f32x4){0.f, 0.f, 0.f, 0.f};

#pragma unroll
    for (int ks = 0; ks < 2; ++ks) {
        const int o0 = (32 * ks + 8 * lg) ^ hswz;     // 8-aligned block
        short8 bhi = *(const short8*)(hc + (o0 >> 1));
        short8 blo = *(const short8*)(hc + 32 + (o0 >> 1));
#pragma unroll
        for (int rf = 0; rf < 7; ++rf) {
            const int aoff = (16 * rf + lr) * HID + 32 * ks + 8 * lg;
            short8 ahi = *(const short8*)(w2hi + aoff);
            short8 alo = *(const short8*)(w2lo + aoff);
            acc2[rf] = __builtin_amdgcn_mfma_f32_16x16x32_bf16(ahi, bhi, acc2[rf], 0, 0, 0);
            acc2[rf] = __builtin_amdgcn_mfma_f32_16x16x32_bf16(ahi, blo, acc2[rf], 0, 0, 0);
            acc2[rf] = __builtin_amdgcn_mfma_f32_16x16x32_bf16(alo, bhi, acc2[rf], 0, 0, 0);
        }
    }

    // ---- bias + pack f16 pairs + store: r = 16rf + 4lg + {0..3}, col gcol
    unsigned int* kb = kern + (size_t)b * RP * DIMN + gcol;
#pragma unroll
    for (int rf = 0; rf < 7; ++rf) {
#pragma unroll
        for (int p = 0; p < 2; ++p) {
            const int r0 = 16 * rf + 4 * lg + 2 * p;
            float k0 = acc2[rf][2 * p + 0] + b2[r0 + 0];
            float k1 = acc2[rf][2 * p + 1] + b2[r0 + 1];
            kb[(size_t)(r0 >> 1) * DIMN] = packf(k0, k1);
        }
    }
}

// ---------------------------------------------------------------------------
// kv extraction: row pair index i and half h for tap k, given group parity.
template <int OFF>
static __device__ inline void extract_kv(const uint4 q[4], float kv[KK][4]) {
#pragma unroll
    for (int k = 0; k < KK; ++k) {
        const int kk = k + OFF;
        const int i  = kk >> 1;
        const int h  = kk & 1;
#pragma unroll
        for (int j = 0; j < 4; ++j) {
            unsigned int u = (&q[i].x)[j];
            half2_t hh = ash2(u);
            kv[k][j] = h ? (float)hh[1] : (float)hh[0];
        }
    }
}

// Involution: one thread per (b, ch, l-quad). kern from packed f16 pairs.
__global__ __launch_bounds__(256) void involution_k(
    const float* __restrict__ x,
    const unsigned int* __restrict__ kern,
    float* __restrict__ out) {
    int t  = blockIdx.x * 256 + threadIdx.x;   // 0 .. 4,194,303
    int lq = t & 1023;
    int ch = (t >> 10) & 255;
    int b  = t >> 18;
    int l  = lq * 4;
    int g  = ch >> 4;                           // wave-uniform

    int rbase = (7 * g) >> 1;
    const unsigned int* kb = kern + ((size_t)b * RP + rbase) * DIMN + l;
    uint4 q[4];
#pragma unroll
    for (int i = 0; i < 4; ++i) q[i] = *(const uint4*)(kb + (size_t)i * DIMN);

    float kv[KK][4];
    if (g & 1) extract_kv<1>(q, kv);
    else       extract_kv<0>(q, kv);

    const float* xrow = x + ((size_t)b * CHN + ch) * DIMN;
    float4 fa = *(const float4*)(xrow + (l > 0 ? l - 4 : 0));
    float4 fb = *(const float4*)(xrow + l);
    float4 fc = *(const float4*)(xrow + (l + 4 < DIMN ? l + 4 : DIMN - 4));

    float xr[10] = { fa.y, fa.z, fa.w, fb.x, fb.y, fb.z, fb.w, fc.x, fc.y, fc.z };
    if (l == 0)        { xr[0] = 0.f; xr[1] = 0.f; xr[2] = 0.f; }
    if (l == DIMN - 4) { xr[7] = 0.f; xr[8] = 0.f; xr[9] = 0.f; }

    float o0 = 0.f, o1 = 0.f, o2 = 0.f, o3 = 0.f;
#pragma unroll
    for (int k = 0; k < KK; ++k) {
        o0 = fmaf(kv[k][0], xr[k + 0], o0);
        o1 = fmaf(kv[k][1], xr[k + 1], o1);
        o2 = fmaf(kv[k][2], xr[k + 2], o2);
        o3 = fmaf(kv[k][3], xr[k + 3], o3);
    }
    *(float4*)(out + ((size_t)b * CHN + ch) * DIMN + l) = make_float4(o0, o1, o2, o3);
}

// ---------------------------------------------------------------------------
extern "C" void kernel_launch(void* const* d_in, const int* in_sizes, int n_in,
                              void* d_out, int out_size, void* d_ws, size_t ws_size,
                              hipStream_t stream) {
    (void)in_sizes; (void)n_in; (void)out_size; (void)ws_size;

    const float* x        = (const float*)d_in[0];
    const float* w1       = (const float*)d_in[1];
    const float* b1       = (const float*)d_in[2];
    const float* bn_gamma = (const float*)d_in[3];
    const float* bn_beta  = (const float*)d_in[4];
    const float* bn_mean  = (const float*)d_in[5];
    const float* bn_var   = (const float*)d_in[6];
    const float* w2       = (const float*)d_in[7];
    const float* b2       = (const float*)d_in[8];
    float*       out      = (float*)d_out;

    unsigned short* w1hi = (unsigned short*)d_ws;          // 16384
    unsigned short* w1lo = w1hi + HID * CHN;               // 16384
    unsigned short* w2hi = w1lo + HID * CHN;               // 7168
    unsigned short* w2lo = w2hi + KGN * HID;               // 7168
    float*          scb  = (float*)(w2lo + KGN * HID);     // 64
    float*          shb  = scb + HID;                      // 64
    unsigned int*   kern = (unsigned int*)(shb + HID);     // 16*56*4096 = 14 MiB

    setup_k<<<(HID * CHN + 255) / 256, 256, 0, stream>>>(
        w1, w2, bn_gamma, bn_beta, bn_mean, bn_var,
        w1hi, w1lo, w2hi, w2lo, scb, shb);
    kerngen_k<<<BB * (DIMN / LT), 256, 0, stream>>>(
        x, w1hi, w1lo, b1, scb, shb, w2hi, w2lo, b2, kern);
    involution_k<<<(BB * CHN * (DIMN / 4)) / 256, 256, 0, stream>>>(x, kern, out);
}

// Round 7
// 60.024 us; speedup vs baseline: 1.4849x; 1.4849x over previous
//
#include <hip/hip_runtime.h>

// Involution1d: B=16, CH=256, DIM=4096, G=16, K=7, PAD=3, hid=64, K*G=112.
// setup (f16 weights) -> kerngen (channel-panel streaming + f16 MFMA,
// kern f16-pairs in ws) -> involution (memory-bound).
#define BB   16
#define CHN  256
#define DIMN 4096
#define KK   7
#define PADK 3
#define HID  64
#define KGN  112
#define RP   56        // kern rows as f16-pairs
#define TLC  128       // columns (locations) per block tile
#define NPAN 8         // channel panels
#define PCH  32        // channels per panel (= one MFMA K-step)
#define XSTD 66        // xs row stride in u32 (= 132 halves)
#define HSTD 132       // row stride in halves for xs/hs
#define BN_EPS 1e-5f

typedef __fp16 half2_t __attribute__((ext_vector_type(2)));
typedef __fp16 half8   __attribute__((ext_vector_type(8)));
typedef float  f32x4   __attribute__((ext_vector_type(4)));

union U32H2 { unsigned int u; half2_t h; };

static __device__ __forceinline__ unsigned int packf(float a, float b) {
    U32H2 t; t.h = __builtin_amdgcn_cvt_pkrtz(a, b); return t.u;
}
static __device__ __forceinline__ half2_t ash2(unsigned int u) { U32H2 t; t.u = u; return t.h; }
static __device__ __forceinline__ __fp16 u16h(unsigned short u) {
    return __builtin_bit_cast(__fp16, u);
}
static __device__ __forceinline__ unsigned short hu16(__fp16 h) {
    return __builtin_bit_cast(unsigned short, h);
}

// ---------------------------------------------------------------------------
// Convert w1 [64][256] and w2 [112][64] to f16 (layout unchanged); BN affine.
__global__ __launch_bounds__(256) void setup_k(
    const float* __restrict__ w1, const float* __restrict__ w2,
    const float* __restrict__ bn_gamma, const float* __restrict__ bn_beta,
    const float* __restrict__ bn_mean,  const float* __restrict__ bn_var,
    __fp16* __restrict__ w1f, __fp16* __restrict__ w2f,
    float* __restrict__ scb, float* __restrict__ shb) {
    int t = blockIdx.x * 256 + threadIdx.x;   // grid covers 16384
    if (t < HID * CHN) w1f[t] = (__fp16)w1[t];
    if (t < KGN * HID) w2f[t] = (__fp16)w2[t];
    if (t < HID) {
        float s = bn_gamma[t] * rsqrtf(bn_var[t] + BN_EPS);
        scb[t] = s;
        shb[t] = bn_beta[t] - bn_mean[t] * s;
    }
}

// ---------------------------------------------------------------------------
// MFMA kernel generator, channel-panel streaming.
// Block = (b, 128-col tile), 4 waves; wave w owns cols [32w, 32w+32).
// Per panel p: stage x[32p..32p+32][l0..l0+128] -> LDS f16 (global reads are
// 2 x 512 B contiguous per instr), one MFMA K-step per panel.
// Fragment maps (16x16x32): A[m][k]: m=lane&15, k=8*(lane>>4)+j;
// B[k][n]: n=lane&15, k=8*(lane>>4)+j; D[m][n]: n=lane&15, m=4*(lane>>4)+reg.
__global__ __launch_bounds__(256) void kerngen_k(
    const float* __restrict__ x,
    const __fp16* __restrict__ w1f,
    const float* __restrict__ b1,
    const float* __restrict__ scb, const float* __restrict__ shb,
    const __fp16* __restrict__ w2f,
    const float* __restrict__ b2,
    unsigned int* __restrict__ kern) {        // [16][56][4096] f16-pairs
    __shared__ unsigned int   xs[2][PCH * XSTD];   // 2 x 8.25 KiB
    __shared__ unsigned short hs[HID * HSTD];      // 16.5 KiB

    const int t    = threadIdx.x;
    const int lr   = t & 15;
    const int lg   = (t >> 4) & 3;
    const int w    = t >> 6;
    const int b    = blockIdx.x >> 5;
    const int l0   = (blockIdx.x & 31) * TLC;
    const int colw = 32 * w;

    // staging assignment: thread covers (ch_local = chl0+8i, col quad colq)
    const int colq = t & 31;
    const int chl0 = t >> 5;            // 0..7

    const float* xg = x + (size_t)b * CHN * DIMN + l0 + 4 * colq;

    // ---- prologue: stage panel 0
    float4 pre[4];
#pragma unroll
    for (int i = 0; i < 4; ++i)
        pre[i] = *(const float4*)(xg + (size_t)(chl0 + 8 * i) * DIMN);
#pragma unroll
    for (int i = 0; i < 4; ++i) {
        uint2 v;
        v.x = packf(pre[i].x, pre[i].y);
        v.y = packf(pre[i].z, pre[i].w);
        *(uint2*)&xs[0][(chl0 + 8 * i) * XSTD + 2 * colq] = v;
    }
    __syncthreads();

    // ---- Phase 1: h = w1 . x   (acc[of][cf], 8 panels)
    f32x4 acc[4][2];
#pragma unroll
    for (int of = 0; of < 4; ++of)
#pragma unroll
        for (int cf = 0; cf < 2; ++cf) acc[of][cf] = (f32x4){0.f, 0.f, 0.f, 0.f};

    for (int p = 0; p < NPAN; ++p) {
        // issue next panel's global loads early (land during this panel's MFMA)
        if (p + 1 < NPAN) {
#pragma unroll
            for (int i = 0; i < 4; ++i)
                pre[i] = *(const float4*)(xg + (size_t)((p + 1) * PCH + chl0 + 8 * i) * DIMN);
        }
        // consume panel p
        const unsigned short* xb16 = (const unsigned short*)xs[p & 1];
        half8 bf0, bf1;
#pragma unroll
        for (int j = 0; j < 8; ++j) {
            bf0[j] = u16h(xb16[(8 * lg + j) * HSTD + colw + lr]);
            bf1[j] = u16h(xb16[(8 * lg + j) * HSTD + colw + 16 + lr]);
        }
#pragma unroll
        for (int of = 0; of < 4; ++of) {
            half8 af = *(const half8*)(w1f + (16 * of + lr) * CHN + PCH * p + 8 * lg);
            acc[of][0] = __builtin_amdgcn_mfma_f32_16x16x32_f16(af, bf0, acc[of][0], 0, 0, 0);
            acc[of][1] = __builtin_amdgcn_mfma_f32_16x16x32_f16(af, bf1, acc[of][1], 0, 0, 0);
        }
        // write next panel (write-late; other buffer)
        if (p + 1 < NPAN) {
            __syncthreads();
#pragma unroll
            for (int i = 0; i < 4; ++i) {
                uint2 v;
                v.x = packf(pre[i].x, pre[i].y);
                v.y = packf(pre[i].z, pre[i].w);
                *(uint2*)&xs[(p + 1) & 1][(chl0 + 8 * i) * XSTD + 2 * colq] = v;
            }
            __syncthreads();
        }
    }

    // ---- bias + relu + BN, h -> LDS f16 [o][col] (wave-private columns)
#pragma unroll
    for (int of = 0; of < 4; ++of) {
#pragma unroll
        for (int r = 0; r < 4; ++r) {
            const int o  = 16 * of + 4 * lg + r;
            const float bo = b1[o], sc = scb[o], sh = shb[o];
#pragma unroll
            for (int cf = 0; cf < 2; ++cf) {
                float hv = fmaxf(acc[of][cf][r] + bo, 0.f) * sc + sh;
                hs[o * HSTD + colw + 16 * cf + lr] = hu16((__fp16)hv);
            }
        }
    }
    // producer wave == consumer wave for these columns -> no barrier.

    // ---- Phase 2: kern = w2 . h   (acc2[rf][cf], 2 K-steps)
    f32x4 acc2[7][2];
#pragma unroll
    for (int rf = 0; rf < 7; ++rf)
#pragma unroll
        for (int cf = 0; cf < 2; ++cf) acc2[rf][cf] = (f32x4){0.f, 0.f, 0.f, 0.f};

#pragma unroll
    for (int ks = 0; ks < 2; ++ks) {
        half8 h0, h1;
#pragma unroll
        for (int j = 0; j < 8; ++j) {
            h0[j] = u16h(hs[(32 * ks + 8 * lg + j) * HSTD + colw + lr]);
            h1[j] = u16h(hs[(32 * ks + 8 * lg + j) * HSTD + colw + 16 + lr]);
        }
#pragma unroll
        for (int rf = 0; rf < 7; ++rf) {
            half8 af = *(const half8*)(w2f + (16 * rf + lr) * HID + 32 * ks + 8 * lg);
            acc2[rf][0] = __builtin_amdgcn_mfma_f32_16x16x32_f16(af, h0, acc2[rf][0], 0, 0, 0);
            acc2[rf][1] = __builtin_amdgcn_mfma_f32_16x16x32_f16(af, h1, acc2[rf][1], 0, 0, 0);
        }
    }

    // ---- bias + pack f16 pairs + store
    unsigned int* kb = kern + (size_t)b * RP * DIMN + l0;
#pragma unroll
    for (int rf = 0; rf < 7; ++rf) {
#pragma unroll
        for (int cf = 0; cf < 2; ++cf) {
#pragma unroll
            for (int pp = 0; pp < 2; ++pp) {
                const int r0  = 16 * rf + 4 * lg + 2 * pp;
                const int col = colw + 16 * cf + lr;
                float k0 = acc2[rf][cf][2 * pp + 0] + b2[r0 + 0];
                float k1 = acc2[rf][cf][2 * pp + 1] + b2[r0 + 1];
                kb[(size_t)(r0 >> 1) * DIMN + col] = packf(k0, k1);
            }
        }
    }
}

// ---------------------------------------------------------------------------
// kv extraction: row pair index i and half h for tap k, given group parity.
template <int OFF>
static __device__ inline void extract_kv(const uint4 q[4], float kv[KK][4]) {
#pragma unroll
    for (int k = 0; k < KK; ++k) {
        const int kk = k + OFF;
        const int i  = kk >> 1;
        const int h  = kk & 1;
#pragma unroll
        for (int j = 0; j < 4; ++j) {
            unsigned int u = (&q[i].x)[j];
            half2_t hh = ash2(u);
            kv[k][j] = h ? (float)hh[1] : (float)hh[0];
        }
    }
}

// Involution: one thread per (b, ch, l-quad). kern from packed f16 pairs.
__global__ __launch_bounds__(256) void involution_k(
    const float* __restrict__ x,
    const unsigned int* __restrict__ kern,
    float* __restrict__ out) {
    int t  = blockIdx.x * 256 + threadIdx.x;   // 0 .. 4,194,303
    int lq = t & 1023;
    int ch = (t >> 10) & 255;
    int b  = t >> 18;
    int l  = lq * 4;
    int g  = ch >> 4;                           // wave-uniform

    int rbase = (7 * g) >> 1;
    const unsigned int* kb = kern + ((size_t)b * RP + rbase) * DIMN + l;
    uint4 q[4];
#pragma unroll
    for (int i = 0; i < 4; ++i) q[i] = *(const uint4*)(kb + (size_t)i * DIMN);

    float kv[KK][4];
    if (g & 1) extract_kv<1>(q, kv);
    else       extract_kv<0>(q, kv);

    const float* xrow = x + ((size_t)b * CHN + ch) * DIMN;
    float4 fa = *(const float4*)(xrow + (l > 0 ? l - 4 : 0));
    float4 fb = *(const float4*)(xrow + l);
    float4 fc = *(const float4*)(xrow + (l + 4 < DIMN ? l + 4 : DIMN - 4));

    float xr[10] = { fa.y, fa.z, fa.w, fb.x, fb.y, fb.z, fb.w, fc.x, fc.y, fc.z };
    if (l == 0)        { xr[0] = 0.f; xr[1] = 0.f; xr[2] = 0.f; }
    if (l == DIMN - 4) { xr[7] = 0.f; xr[8] = 0.f; xr[9] = 0.f; }

    float o0 = 0.f, o1 = 0.f, o2 = 0.f, o3 = 0.f;
#pragma unroll
    for (int k = 0; k < KK; ++k) {
        o0 = fmaf(kv[k][0], xr[k + 0], o0);
        o1 = fmaf(kv[k][1], xr[k + 1], o1);
        o2 = fmaf(kv[k][2], xr[k + 2], o2);
        o3 = fmaf(kv[k][3], xr[k + 3], o3);
    }
    *(float4*)(out + ((size_t)b * CHN + ch) * DIMN + l) = make_float4(o0, o1, o2, o3);
}

// ---------------------------------------------------------------------------
extern "C" void kernel_launch(void* const* d_in, const int* in_sizes, int n_in,
                              void* d_out, int out_size, void* d_ws, size_t ws_size,
                              hipStream_t stream) {
    (void)in_sizes; (void)n_in; (void)out_size; (void)ws_size;

    const float* x        = (const float*)d_in[0];
    const float* w1       = (const float*)d_in[1];
    const float* b1       = (const float*)d_in[2];
    const float* bn_gamma = (const float*)d_in[3];
    const float* bn_beta  = (const float*)d_in[4];
    const float* bn_mean  = (const float*)d_in[5];
    const float* bn_var   = (const float*)d_in[6];
    const float* w2       = (const float*)d_in[7];
    const float* b2       = (const float*)d_in[8];
    float*       out      = (float*)d_out;

    __fp16*       w1f  = (__fp16*)d_ws;                    // 16384 f16
    __fp16*       w2f  = w1f + HID * CHN;                  // 7168 f16
    float*        scb  = (float*)(w2f + KGN * HID);        // 64
    float*        shb  = scb + HID;                        // 64
    unsigned int* kern = (unsigned int*)(shb + HID);       // 16*56*4096 = 14 MiB

    setup_k<<<(HID * CHN + 255) / 256, 256, 0, stream>>>(
        w1, w2, bn_gamma, bn_beta, bn_mean, bn_var, w1f, w2f, scb, shb);
    kerngen_k<<<BB * (DIMN / TLC), 256, 0, stream>>>(
        x, w1f, b1, scb, shb, w2f, b2, kern);
    involution_k<<<(BB * CHN * (DIMN / 4)) / 256, 256, 0, stream>>>(x, kern, out);
}